// Round 2
// baseline (160.685 us; speedup 1.0000x reference)
//
#include <hip/hip_runtime.h>
#include <cstdint>
#include <cstddef>

#define THETA 1.2f
#define XI 0.3f
#define BDIM 8192
#define DDIM 512
#define NTILE 64           // 8192 / 128
#define NBLOCKS 2080       // 64*65/2 upper-tri tiles

typedef __bf16 bf16x8 __attribute__((ext_vector_type(8)));
typedef float f32x4 __attribute__((ext_vector_type(4)));

__device__ inline unsigned short f2bf(float f) {
    union { float f; unsigned int u; } a; a.f = f;
    unsigned int r = a.u + 0x7fffu + ((a.u >> 16) & 1u);  // RN-even
    return (unsigned short)(r >> 16);
}

// Kernel 1: per-row L2 normalize fp32 -> bf16 bits, emit sq[row]=||n||^2, zero acc+counter.
__global__ __launch_bounds__(256) void normalize_rows(
    const float* __restrict__ x, unsigned short* __restrict__ nbf,
    float* __restrict__ sq, double* __restrict__ acc, unsigned int* __restrict__ counter)
{
    if (blockIdx.x == 0 && threadIdx.x == 0) { *acc = 0.0; *counter = 0u; }
    int row = blockIdx.x * 4 + (threadIdx.x >> 6);
    int l = threadIdx.x & 63;
    const float4* xr = (const float4*)(x + (size_t)row * DDIM);
    float4 v0 = xr[l];
    float4 v1 = xr[l + 64];
    float s = v0.x*v0.x + v0.y*v0.y + v0.z*v0.z + v0.w*v0.w
            + v1.x*v1.x + v1.y*v1.y + v1.z*v1.z + v1.w*v1.w;
    #pragma unroll
    for (int m = 1; m < 64; m <<= 1) s += __shfl_xor(s, m);
    float rn = rsqrtf(s);
    ushort4 o0, o1;
    o0.x = f2bf(v0.x * rn); o0.y = f2bf(v0.y * rn);
    o0.z = f2bf(v0.z * rn); o0.w = f2bf(v0.w * rn);
    o1.x = f2bf(v1.x * rn); o1.y = f2bf(v1.y * rn);
    o1.z = f2bf(v1.z * rn); o1.w = f2bf(v1.w * rn);
    ushort4* nr = (ushort4*)(nbf + (size_t)row * DDIM);
    nr[l] = o0; nr[l + 64] = o1;
    if (l == 0) sq[row] = s * rn * rn;
}

// Kernel 2: 1D triangular grid of 128x128 Gram tiles, 16x16x32 bf16 MFMA,
// double-buffered BK=32 staging (1 barrier/iter), XOR bank swizzle,
// fused hinge reduction + last-block finalize.
__global__ __launch_bounds__(256) void gram_hinge(
    const unsigned short* __restrict__ nbf, const float* __restrict__ sq,
    const int* __restrict__ y, double* __restrict__ acc,
    unsigned int* __restrict__ counter, float* __restrict__ out)
{
    // decode upper-tri tile (bi, bj), bj >= bi
    int t = blockIdx.x;
    int bi = (int)((129.0 - sqrt(16641.0 - 8.0 * (double)t)) * 0.5);
    while ((bi + 1) * 64 - ((bi + 1) * bi) / 2 <= t) ++bi;
    while (bi * 64 - (bi * (bi - 1)) / 2 > t) --bi;
    int bj = bi + (t - (bi * 64 - (bi * (bi - 1)) / 2));

    // dbuf LDS: [buf][chunk(8)][row16][kg4][8 shorts]; 8 KB per buf per matrix
    __shared__ unsigned short As[2 * 128 * 32];
    __shared__ unsigned short Bs[2 * 128 * 32];
    __shared__ float wpart[4];

    int tid = threadIdx.x;
    int w = tid >> 6, l = tid & 63;
    int wr = w >> 1, wc = w & 1;     // wave 2x2 -> 64x64 subtile
    int lr = l & 15, q = l >> 4;

    f32x4 accv[4][4] = {};

    const unsigned short* gA = nbf + (size_t)bi * 128 * DDIM;
    const unsigned short* gB = nbf + (size_t)bj * 128 * DDIM;
    int srow = l >> 2;                                   // row within 16-row chunk
    int kg = (l & 3) ^ (srow & 3) ^ ((srow >> 2) & 3);   // XOR bank swizzle
    int scol = kg * 8;

    // fragment-read swizzle: slot holding k-group q for row lr
    int perm = q ^ (lr & 3) ^ ((lr >> 2) & 3);

    // prologue: stage k0=0 into buf 0
    #pragma unroll
    for (int c2 = 0; c2 < 2; ++c2) {
        int chunk = w + c2 * 4;
        int r = chunk * 16 + srow;
        __builtin_amdgcn_global_load_lds(
            (const __attribute__((address_space(1))) void*)(gA + (size_t)r * DDIM + scol),
            (__attribute__((address_space(3))) void*)(As + chunk * 512), 16, 0, 0);
        __builtin_amdgcn_global_load_lds(
            (const __attribute__((address_space(1))) void*)(gB + (size_t)r * DDIM + scol),
            (__attribute__((address_space(3))) void*)(Bs + chunk * 512), 16, 0, 0);
    }

    for (int it = 0; it < 16; ++it) {
        __syncthreads();   // drains vmcnt: buf[it&1] staged, prev LDS reads done
        int cur = (it & 1) * 4096, nxt = 4096 - cur;
        if (it + 1 < 16) {
            int k0 = (it + 1) * 32;
            #pragma unroll
            for (int c2 = 0; c2 < 2; ++c2) {
                int chunk = w + c2 * 4;
                int r = chunk * 16 + srow;
                __builtin_amdgcn_global_load_lds(
                    (const __attribute__((address_space(1))) void*)(gA + (size_t)r * DDIM + k0 + scol),
                    (__attribute__((address_space(3))) void*)(As + nxt + chunk * 512), 16, 0, 0);
                __builtin_amdgcn_global_load_lds(
                    (const __attribute__((address_space(1))) void*)(gB + (size_t)r * DDIM + k0 + scol),
                    (__attribute__((address_space(3))) void*)(Bs + nxt + chunk * 512), 16, 0, 0);
            }
        }
        const bf16x8* Av = (const bf16x8*)(As + cur);
        const bf16x8* Bv = (const bf16x8*)(Bs + cur);
        bf16x8 af[4], bfr[4];
        #pragma unroll
        for (int mi = 0; mi < 4; ++mi) af[mi]  = Av[(wr * 64 + mi * 16 + lr) * 4 + perm];
        #pragma unroll
        for (int ni = 0; ni < 4; ++ni) bfr[ni] = Bv[(wc * 64 + ni * 16 + lr) * 4 + perm];
        #pragma unroll
        for (int mi = 0; mi < 4; ++mi)
            #pragma unroll
            for (int ni = 0; ni < 4; ++ni)
                accv[mi][ni] = __builtin_amdgcn_mfma_f32_16x16x32_bf16(
                    af[mi], bfr[ni], accv[mi][ni], 0, 0, 0);
    }

    // Epilogue: C/D layout col=lane&15, row=q*4+reg (verified m89/m91).
    int jbase = bj * 128 + wc * 64 + lr;
    float sqj[4]; int yj[4];
    #pragma unroll
    for (int ni = 0; ni < 4; ++ni) {
        int gj = jbase + ni * 16;
        sqj[ni] = sq[gj]; yj[ni] = y[gj];
    }
    float local = 0.f;
    #pragma unroll
    for (int mi = 0; mi < 4; ++mi) {
        #pragma unroll
        for (int r = 0; r < 4; ++r) {
            int gi = bi * 128 + wr * 64 + mi * 16 + q * 4 + r;
            float sqi = sq[gi]; int yi = y[gi];
            #pragma unroll
            for (int ni = 0; ni < 4; ++ni) {
                int gj = jbase + ni * 16;
                float G = accv[mi][ni][r];
                float d2 = sqi + sqj[ni] - 2.0f * G;
                float h = fmaxf(THETA - d2, 0.0f);
                float tv = XI + ((yi == yj[ni]) ? h : -h);
                if (gj >= gi) local += tv;   // only matters on diagonal tiles
            }
        }
    }
    #pragma unroll
    for (int off = 32; off > 0; off >>= 1) local += __shfl_down(local, off);
    if (l == 0) wpart[w] = local;
    __syncthreads();
    if (tid == 0) {
        double ssum = (double)wpart[0] + (double)wpart[1]
                    + (double)wpart[2] + (double)wpart[3];
        atomicAdd(acc, ssum);
        __threadfence();
        unsigned int ticket = atomicAdd(counter, 1u);
        if (ticket == NBLOCKS - 1) {
            __threadfence();
            double total = atomicAdd(acc, 0.0);   // coherent read
            const double m = 1.0 / ((double)BDIM * (double)BDIM - (double)BDIM);
            out[0] = (float)(total * m);
        }
    }
}

extern "C" void kernel_launch(void* const* d_in, const int* in_sizes, int n_in,
                              void* d_out, int out_size, void* d_ws, size_t ws_size,
                              hipStream_t stream) {
    const float* x = (const float*)d_in[0];
    const int* y = (const int*)d_in[1];
    float* out = (float*)d_out;

    unsigned short* nbf = (unsigned short*)d_ws;                        // 8 MB bf16 bits
    char* p = (char*)d_ws + (size_t)BDIM * DDIM * 2;
    float* sq = (float*)p;                                              // 32 KB
    double* acc = (double*)(p + (size_t)BDIM * 4);
    unsigned int* counter = (unsigned int*)(p + (size_t)BDIM * 4 + 8);

    normalize_rows<<<BDIM / 4, 256, 0, stream>>>(x, nbf, sq, acc, counter);
    gram_hinge<<<NBLOCKS, 256, 0, stream>>>(nbf, sq, y, acc, counter, out);
}

// Round 3
// 143.094 us; speedup vs baseline: 1.1229x; 1.1229x over previous
//
#include <hip/hip_runtime.h>
#include <cstdint>
#include <cstddef>

#define THETA 1.2f
#define XI 0.3f
#define BDIM 8192
#define DDIM 512
#define NWORK 2080         // 64*65/2 working upper-tri tiles

typedef float f32x4 __attribute__((ext_vector_type(4)));
typedef int i32x8 __attribute__((ext_vector_type(8)));

// Kernel 1: per-row L2 normalize fp32 -> fp8 e4m3 (OCP, HW cvt), sq[row]=||n||^2, zero acc+counter.
// One wave per row, lane l handles k = 8l..8l+7.
__global__ __launch_bounds__(256) void normalize_rows(
    const float* __restrict__ x, unsigned char* __restrict__ nf8,
    float* __restrict__ sq, double* __restrict__ acc, unsigned int* __restrict__ counter)
{
    if (blockIdx.x == 0 && threadIdx.x == 0) { *acc = 0.0; *counter = 0u; }
    int row = blockIdx.x * 4 + (threadIdx.x >> 6);
    int l = threadIdx.x & 63;
    const float4* xr = (const float4*)(x + (size_t)row * DDIM);
    float4 v0 = xr[2 * l];
    float4 v1 = xr[2 * l + 1];
    float s = v0.x*v0.x + v0.y*v0.y + v0.z*v0.z + v0.w*v0.w
            + v1.x*v1.x + v1.y*v1.y + v1.z*v1.z + v1.w*v1.w;
    #pragma unroll
    for (int m = 1; m < 64; m <<= 1) s += __shfl_xor(s, m);
    float rn = rsqrtf(s);
    int pkL = __builtin_amdgcn_cvt_pk_fp8_f32(v0.x * rn, v0.y * rn, 0, false);
    pkL     = __builtin_amdgcn_cvt_pk_fp8_f32(v0.z * rn, v0.w * rn, pkL, true);
    int pkH = __builtin_amdgcn_cvt_pk_fp8_f32(v1.x * rn, v1.y * rn, 0, false);
    pkH     = __builtin_amdgcn_cvt_pk_fp8_f32(v1.z * rn, v1.w * rn, pkH, true);
    ((int2*)(nf8 + (size_t)row * DDIM))[l] = make_int2(pkL, pkH);
    if (l == 0) sq[row] = s * rn * rn;
}

// Kernel 2: 128x128 Gram tiles, fp8 via mfma_scale_f32_16x16x128_f8f6f4 (scales=1.0),
// BK=128 -> 4 K-iters, single-buffered. 2D grid, bj<bi exits. Fused hinge + ticket finalize.
__global__ __launch_bounds__(256) void gram_hinge(
    const unsigned char* __restrict__ nf8, const float* __restrict__ sq,
    const int* __restrict__ y, double* __restrict__ acc,
    unsigned int* __restrict__ counter, float* __restrict__ out)
{
    int bi = blockIdx.x, bj = blockIdx.y;
    if (bj < bi) return;

    __shared__ unsigned char As[128 * 128];  // 16 KB, row-major 128-B rows, light granule swizzle
    __shared__ unsigned char Bs[128 * 128];
    __shared__ float wpart[4];

    int tid = threadIdx.x;
    int w = tid >> 6, l = tid & 63;
    int wr = w >> 1, wc = w & 1;     // wave 2x2 -> 64x64 subtile
    int lr = l & 15, q = l >> 4;

    f32x4 accv[4][4] = {};

    const unsigned char* gA = nf8 + (size_t)bi * 128 * DDIM;
    const unsigned char* gB = nf8 + (size_t)bj * 128 * DDIM;

    // staging: per instr, 64 lanes stage 8 rows x 128 B. lane l -> row srow=l>>3,
    // LDS granule l&7 holds global granule (l&7) ^ ((srow&3)<<1)  (light swizzle:
    // keeps 32/64-B global segments lane-contiguous; frag reads become free 2-way).
    int srow = l >> 3;
    int gg = (l & 7) ^ ((srow & 3) << 1);
    int sw_r = (lr & 3) << 1;   // swizzle term for this lane's fragment rows

    for (int it = 0; it < 4; ++it) {
        int k0 = it * 128;
        __syncthreads();   // prev iter's LDS reads done
        #pragma unroll
        for (int i = 0; i < 4; ++i) {
            int ch = w * 4 + i;              // 16 chunks of 8 rows
            int r = ch * 8 + srow;
            __builtin_amdgcn_global_load_lds(
                (const __attribute__((address_space(1))) void*)(gA + (size_t)r * DDIM + k0 + gg * 16),
                (__attribute__((address_space(3))) void*)(As + ch * 1024), 16, 0, 0);
            __builtin_amdgcn_global_load_lds(
                (const __attribute__((address_space(1))) void*)(gB + (size_t)r * DDIM + k0 + gg * 16),
                (__attribute__((address_space(3))) void*)(Bs + ch * 1024), 16, 0, 0);
        }
        __syncthreads();   // staging visible

        // fragments: lane (lr,q) needs k = q*32..q*32+31 -> global granules 2q, 2q+1
        i32x8 af[4], bfr[4];
        #pragma unroll
        for (int mi = 0; mi < 4; ++mi) {
            int r = wr * 64 + mi * 16 + lr;
            const int4* p0 = (const int4*)(As + r * 128 + (((q << 1) | 0) ^ sw_r) * 16);
            const int4* p1 = (const int4*)(As + r * 128 + (((q << 1) | 1) ^ sw_r) * 16);
            int4 a0 = *p0, a1 = *p1;
            af[mi][0] = a0.x; af[mi][1] = a0.y; af[mi][2] = a0.z; af[mi][3] = a0.w;
            af[mi][4] = a1.x; af[mi][5] = a1.y; af[mi][6] = a1.z; af[mi][7] = a1.w;
        }
        #pragma unroll
        for (int ni = 0; ni < 4; ++ni) {
            int r = wc * 64 + ni * 16 + lr;
            const int4* p0 = (const int4*)(Bs + r * 128 + (((q << 1) | 0) ^ sw_r) * 16);
            const int4* p1 = (const int4*)(Bs + r * 128 + (((q << 1) | 1) ^ sw_r) * 16);
            int4 b0 = *p0, b1 = *p1;
            bfr[ni][0] = b0.x; bfr[ni][1] = b0.y; bfr[ni][2] = b0.z; bfr[ni][3] = b0.w;
            bfr[ni][4] = b1.x; bfr[ni][5] = b1.y; bfr[ni][6] = b1.z; bfr[ni][7] = b1.w;
        }
        #pragma unroll
        for (int mi = 0; mi < 4; ++mi)
            #pragma unroll
            for (int ni = 0; ni < 4; ++ni)
                accv[mi][ni] = __builtin_amdgcn_mfma_scale_f32_16x16x128_f8f6f4(
                    af[mi], bfr[ni], accv[mi][ni],
                    0, 0,                    // cbsz=fp8(e4m3), blgp=fp8(e4m3)
                    0, 0x7F7F7F7F,           // opsel_a, scale_a = 1.0 (E8M0 bias 127)
                    0, 0x7F7F7F7F);          // opsel_b, scale_b = 1.0

    }

    // Epilogue: C/D layout col=lane&15, row=q*4+reg (shape-determined, m127/m128).
    int jbase = bj * 128 + wc * 64 + lr;
    float sqj[4]; int yj[4];
    #pragma unroll
    for (int ni = 0; ni < 4; ++ni) {
        int gj = jbase + ni * 16;
        sqj[ni] = sq[gj]; yj[ni] = y[gj];
    }
    float local = 0.f;
    #pragma unroll
    for (int mi = 0; mi < 4; ++mi) {
        #pragma unroll
        for (int r = 0; r < 4; ++r) {
            int gi = bi * 128 + wr * 64 + mi * 16 + q * 4 + r;
            float sqi = sq[gi]; int yi = y[gi];
            #pragma unroll
            for (int ni = 0; ni < 4; ++ni) {
                int gj = jbase + ni * 16;
                float G = accv[mi][ni][r];
                float d2 = sqi + sqj[ni] - 2.0f * G;
                float h = fmaxf(THETA - d2, 0.0f);
                float tv = XI + ((yi == yj[ni]) ? h : -h);
                if (gj >= gi) local += tv;
            }
        }
    }
    #pragma unroll
    for (int off = 32; off > 0; off >>= 1) local += __shfl_down(local, off);
    if (l == 0) wpart[w] = local;
    __syncthreads();
    if (tid == 0) {
        double ssum = (double)wpart[0] + (double)wpart[1]
                    + (double)wpart[2] + (double)wpart[3];
        atomicAdd(acc, ssum);
        __threadfence();
        unsigned int ticket = atomicAdd(counter, 1u);
        if (ticket == NWORK - 1) {
            __threadfence();
            double total = atomicAdd(acc, 0.0);
            const double m = 1.0 / ((double)BDIM * (double)BDIM - (double)BDIM);
            out[0] = (float)(total * m);
        }
    }
}

extern "C" void kernel_launch(void* const* d_in, const int* in_sizes, int n_in,
                              void* d_out, int out_size, void* d_ws, size_t ws_size,
                              hipStream_t stream) {
    const float* x = (const float*)d_in[0];
    const int* y = (const int*)d_in[1];
    float* out = (float*)d_out;

    unsigned char* nf8 = (unsigned char*)d_ws;                          // 4 MB fp8
    char* p = (char*)d_ws + (size_t)BDIM * DDIM;
    float* sq = (float*)p;                                              // 32 KB
    double* acc = (double*)(p + (size_t)BDIM * 4);
    unsigned int* counter = (unsigned int*)(p + (size_t)BDIM * 4 + 8);

    normalize_rows<<<BDIM / 4, 256, 0, stream>>>(x, nf8, sq, acc, counter);
    gram_hinge<<<dim3(64, 64), 256, 0, stream>>>(nf8, sq, y, acc, counter, out);
}